// Round 13
// baseline (46.235 us; speedup 1.0000x reference)
//
#include <hip/hip_runtime.h>
#include <hip/hip_bf16.h>
#include <math.h>

typedef float f4 __attribute__((ext_vector_type(4)));
typedef float f32x4 __attribute__((ext_vector_type(4)));
typedef short bf16x8 __attribute__((ext_vector_type(8)));
typedef unsigned int u32x4 __attribute__((ext_vector_type(4)));

#define D      2048
#define NE     64
#define TOKB   16               // tokens per block (shared by all 8 waves)
#define KSPLIT 8                // waves per block, k-split in-block
#define KRNG   (D / KSPLIT)     // 256 k per wave
#define KCH    32               // k per chunk
#define NCH    (KRNG / KCH)     // 8 chunks per wave
#define CSTR   68               // f32 stride of reduction rows

__device__ __forceinline__ unsigned short bf16rne(float f) {
    unsigned int u = __builtin_bit_cast(unsigned int, f);
    u += 0x7fffu + ((u >> 16) & 1u);
    return (unsigned short)(u >> 16);
}
__device__ __forceinline__ float bf2f(unsigned short h) {
    unsigned int u = (unsigned int)h << 16;
    return __builtin_bit_cast(float, u);
}

// ---- kernel 0: W -> packed bf16 hi/lo in MFMA B-frag order ----
// Wpk[(kc*4 + et)*512 + l*8 + j] = W[et*16 + (l&15)][kc*32 + (l>>4)*8 + j]
__global__ __launch_bounds__(256)
void wprep(const float* __restrict__ W,
           unsigned short* __restrict__ Whp,
           unsigned short* __restrict__ Wlp)
{
    const int i  = blockIdx.x * 256 + threadIdx.x;   // 131072
    const int j  = i & 7;
    const int l  = (i >> 3) & 63;
    const int et = (i >> 9) & 3;
    const int kc = i >> 11;
    const int e  = et * 16 + (l & 15);
    const int k  = kc * 32 + (l >> 4) * 8 + j;
    const float w = W[(size_t)e * D + k];
    const unsigned short h = bf16rne(w);
    Whp[i] = h;
    Wlp[i] = bf16rne(w - bf2f(h));
}

// hi/lo split of a float pair via HW v_cvt_pk_bf16_f32.
// __builtin_memcpy (not bit_cast): __hip_bfloat162 isn't trivially copyable.
#define CVTPAIR(F0, F1, HOUT, LOUT) {                                        \
    __hip_bfloat162 hp_ = __float22bfloat162_rn(make_float2((F0), (F1)));    \
    unsigned hu_; __builtin_memcpy(&hu_, &hp_, 4);                           \
    const float h0_ = __builtin_bit_cast(float, hu_ << 16);                  \
    const float h1_ = __builtin_bit_cast(float, hu_ & 0xffff0000u);          \
    __hip_bfloat162 lp_ = __float22bfloat162_rn(                             \
        make_float2((F0) - h0_, (F1) - h1_));                                \
    unsigned lu_; __builtin_memcpy(&lu_, &lp_, 4);                           \
    HOUT = hu_;                                                              \
    LOUT = lu_;                                                              \
}

// ---- kernel 1: fused split-MFMA logits + in-block reduce + top2 + softmax ----
// NO LDS in the main loop: lane l's A-frag IS its own 8 contiguous f32 of x
// (row=l&15, k-slice=(l>>4)*8 — layout hardware-verified passing in r6).
// Depth-2 x prefetch (parity sets), B all-up-front per chunk (r9/r10's
// working pattern), CVT block placed between B-issue and B-use as latency
// cover. Live set ~80 VGPR -> launch_bounds(512,6): 6 waves/SIMD.
__global__ __launch_bounds__(512, 6)
void moe_fused(const float* __restrict__ x,
               const unsigned short* __restrict__ Whp,
               const unsigned short* __restrict__ Wlp,
               float* __restrict__ out, int ntok)
{
    __shared__ float cred[KSPLIT][TOKB * CSTR];   // 34.8 KB, epilogue only

    const int t    = threadIdx.x;
    const int w    = t >> 6;            // wave id = k-split id (0..7)
    const int l    = t & 63;
    const int tok0 = blockIdx.x * TOKB;

    const int ar  = l & 15;             // A row (token)
    const int akb = (l >> 4) * 8;       // k-slice within 32-k chunk

    const float* xa = x + (size_t)(tok0 + ar) * D + w * KRNG + akb;
    // packed W: wave base kc = w*8 -> offset w*8*4*512 = w*16384 ushorts
    const unsigned short* whp = Whp + (size_t)w * 16384 + l * 8;
    const unsigned short* wlp = Wlp + (size_t)w * 16384 + l * 8;

#define LOADX(ch, R0, R1) { \
    const float* p_ = xa + (ch) * KCH; \
    R0 = *(const f4*)(p_);     \
    R1 = *(const f4*)(p_ + 4); }

    // one chunk: 8 B-loads up front, CVT (covers B latency), 12 MFMA
#define CHUNK(ch, R0, R1) { \
    bf16x8 bh[4], bl[4]; \
    _Pragma("unroll") \
    for (int et = 0; et < 4; ++et) { \
        const size_t o_ = (size_t)(4 * (ch) + et) * 512; \
        bh[et] = *(const bf16x8*)(whp + o_); \
        bl[et] = *(const bf16x8*)(wlp + o_); \
    } \
    unsigned hu0_, hu1_, hu2_, hu3_, lu0_, lu1_, lu2_, lu3_; \
    CVTPAIR(R0.x, R0.y, hu0_, lu0_); \
    CVTPAIR(R0.z, R0.w, hu1_, lu1_); \
    CVTPAIR(R1.x, R1.y, hu2_, lu2_); \
    CVTPAIR(R1.z, R1.w, hu3_, lu3_); \
    const u32x4 hv_ = {hu0_, hu1_, hu2_, hu3_}; \
    const u32x4 lv_ = {lu0_, lu1_, lu2_, lu3_}; \
    const bf16x8 ah = __builtin_bit_cast(bf16x8, hv_); \
    const bf16x8 al = __builtin_bit_cast(bf16x8, lv_); \
    if ((ch) + 2 < NCH) LOADX((ch) + 2, R0, R1); \
    _Pragma("unroll") \
    for (int et = 0; et < 4; ++et) { \
        acc[et] = __builtin_amdgcn_mfma_f32_16x16x32_bf16(ah, bh[et], acc[et], 0, 0, 0); \
        acc[et] = __builtin_amdgcn_mfma_f32_16x16x32_bf16(ah, bl[et], acc[et], 0, 0, 0); \
        acc[et] = __builtin_amdgcn_mfma_f32_16x16x32_bf16(al, bh[et], acc[et], 0, 0, 0); \
    } }

    const f32x4 zz = {0.f, 0.f, 0.f, 0.f};
    f32x4 acc[4] = {zz, zz, zz, zz};

    f4 xE0, xE1, xO0, xO1;              // depth-2 parity prefetch sets

    LOADX(0, xE0, xE1);
    LOADX(1, xO0, xO1);

#pragma unroll
    for (int ch = 0; ch < NCH; ch += 2) {
        CHUNK(ch,     xE0, xE1);        // consumes xE, refills with ch+2
        CHUNK(ch + 1, xO0, xO1);        // consumes xO, refills with ch+3
    }

#undef LOADX
#undef CHUNK

    // ---- per-wave partials -> LDS ----
    // C/D layout (verified r4): token = (l>>4)*4 + r, expert = et*16 + (l&15)
#pragma unroll
    for (int et = 0; et < 4; ++et)
#pragma unroll
        for (int r = 0; r < 4; ++r) {
            const int tokl = (l >> 4) * 4 + r;
            cred[w][tokl * CSTR + et * 16 + (l & 15)] = acc[et][r];
        }
    __syncthreads();

    // ---- reduce 8 k-splits + top-2 + softmax (128 active threads) ----
    if (t < TOKB * 8) {
        const int tokl = t >> 3;        // 0..15
        const int eg   = t & 7;         // expert octet
        f4 s0 = {0.f,0.f,0.f,0.f}, s1 = {0.f,0.f,0.f,0.f};
#pragma unroll
        for (int ww = 0; ww < KSPLIT; ++ww) {
            const float* cw = &cred[ww][tokl * CSTR + eg * 8];
            s0 += *(const f4*)cw;
            s1 += *(const f4*)(cw + 4);
        }
        const float vv[8] = {s0.x, s0.y, s0.z, s0.w, s1.x, s1.y, s1.z, s1.w};
        float m1 = -INFINITY, m2 = -INFINITY;
        int i1 = 0, i2 = 0;
#pragma unroll
        for (int j = 0; j < 8; ++j) {   // ids ascending: strict > = lowest-index tie-break
            const float v = vv[j];
            const int id = eg * 8 + j;
            if (v > m1)      { m2 = m1; i2 = i1; m1 = v; i1 = id; }
            else if (v > m2) { m2 = v;  i2 = id; }
        }
#pragma unroll
        for (int m = 1; m < 8; m <<= 1) {
            const float om1 = __shfl_xor(m1, m);
            const int   oi1 = __shfl_xor(i1, m);
            const float om2 = __shfl_xor(m2, m);
            const int   oi2 = __shfl_xor(i2, m);
            const bool b1 = (om1 > m1) || (om1 == m1 && oi1 < i1);
            const float c2v = b1 ? m1 : om1;  const int c2i = b1 ? i1 : oi1;
            const float c3v = b1 ? om2 : m2;  const int c3i = b1 ? oi2 : i2;
            if (b1) { m1 = om1; i1 = oi1; }
            const bool b2 = (c3v > c2v) || (c3v == c2v && c3i < c2i);
            m2 = b2 ? c3v : c2v;  i2 = b2 ? c3i : c2i;
        }
        if (eg == 0) {
            const int tok = tok0 + tokl;
            out[(size_t)tok * 2 + 0] = (float)i1;
            out[(size_t)tok * 2 + 1] = (float)i2;
            const float p1 = 1.0f / (1.0f + expf(m2 - m1));   // stable: m2 <= m1
            float* vals = out + (size_t)ntok * 2;
            vals[(size_t)tok * 2 + 0] = p1;
            vals[(size_t)tok * 2 + 1] = 1.0f - p1;
        }
    }
}

extern "C" void kernel_launch(void* const* d_in, const int* in_sizes, int n_in,
                              void* d_out, int out_size, void* d_ws, size_t ws_size,
                              hipStream_t stream)
{
    const float* x = (const float*)d_in[0];
    const float* W = (const float*)d_in[1];
    float* out = (float*)d_out;
    unsigned short* Whp = (unsigned short*)d_ws;
    unsigned short* Wlp = Whp + (size_t)NE * D;

    const int ntok = in_sizes[0] / D;                 // 16384
    wprep<<<(NE * D) / 256, 256, 0, stream>>>(W, Whp, Wlp);
    moe_fused<<<ntok / TOKB, 512, 0, stream>>>(x, Whp, Wlp, out, ntok);
}

// Round 15
// 45.519 us; speedup vs baseline: 1.0157x; 1.0157x over previous
//
#include <hip/hip_runtime.h>
#include <hip/hip_bf16.h>
#include <math.h>

typedef float f4 __attribute__((ext_vector_type(4)));
typedef float f32x4 __attribute__((ext_vector_type(4)));
typedef short bf16x8 __attribute__((ext_vector_type(8)));
typedef unsigned int u32x4 __attribute__((ext_vector_type(4)));

#define D      2048
#define NE     64
#define TOKB   16               // tokens per block (shared by all 8 waves)
#define KSPLIT 8                // waves per block, k-split in-block
#define KRNG   (D / KSPLIT)     // 256 k per wave
#define KCH    32               // k per chunk
#define NCH    (KRNG / KCH)     // 8 chunks per wave
#define CSTR   68               // f32 stride of reduction rows

__device__ __forceinline__ unsigned short bf16rne(float f) {
    unsigned int u = __builtin_bit_cast(unsigned int, f);
    u += 0x7fffu + ((u >> 16) & 1u);
    return (unsigned short)(u >> 16);
}
__device__ __forceinline__ float bf2f(unsigned short h) {
    unsigned int u = (unsigned int)h << 16;
    return __builtin_bit_cast(float, u);
}

// ---- kernel 0: W -> packed bf16 hi/lo in MFMA B-frag order ----
// Wpk[(kc*4 + et)*512 + l*8 + j] = W[et*16 + (l&15)][kc*32 + (l>>4)*8 + j]
__global__ __launch_bounds__(256)
void wprep(const float* __restrict__ W,
           unsigned short* __restrict__ Whp,
           unsigned short* __restrict__ Wlp)
{
    const int i  = blockIdx.x * 256 + threadIdx.x;   // 131072
    const int j  = i & 7;
    const int l  = (i >> 3) & 63;
    const int et = (i >> 9) & 3;
    const int kc = i >> 11;
    const int e  = et * 16 + (l & 15);
    const int k  = kc * 32 + (l >> 4) * 8 + j;
    const float w = W[(size_t)e * D + k];
    const unsigned short h = bf16rne(w);
    Whp[i] = h;
    Wlp[i] = bf16rne(w - bf2f(h));
}

// hi/lo split of a float pair via HW v_cvt_pk_bf16_f32.
#define CVTPAIR(F0, F1, HOUT, LOUT) {                                        \
    __hip_bfloat162 hp_ = __float22bfloat162_rn(make_float2((F0), (F1)));    \
    unsigned hu_; __builtin_memcpy(&hu_, &hp_, 4);                           \
    const float h0_ = __builtin_bit_cast(float, hu_ << 16);                  \
    const float h1_ = __builtin_bit_cast(float, hu_ & 0xffff0000u);          \
    __hip_bfloat162 lp_ = __float22bfloat162_rn(                             \
        make_float2((F0) - h0_, (F1) - h1_));                                \
    unsigned lu_; __builtin_memcpy(&lu_, &lp_, 4);                           \
    HOUT = hu_;                                                              \
    LOUT = lu_;                                                              \
}

// forced 16B global load: asm output keeps the dest registers LIVE from issue
// to use — the allocator cannot sink it (r6/r11/r13 failure mode).
#define GL16(dst, ptr) \
    asm volatile("global_load_dwordx4 %0, %1, off" : "=v"(dst) : "v"(ptr) : "memory")

// counted waits (T4). sched_barrier(0) stops MFMA/CVT hoisting (rule #18).
#define WAIT10 { asm volatile("s_waitcnt vmcnt(10)" ::: "memory"); \
                 __builtin_amdgcn_sched_barrier(0); }
#define WAIT0  { asm volatile("s_waitcnt vmcnt(0)"  ::: "memory"); \
                 __builtin_amdgcn_sched_barrier(0); }

// ---- kernel 1: fused split-MFMA logits + in-block reduce + top2 + softmax ----
// r13 geometry (no LDS in main loop; lane l's A-frag = own 8 contiguous f32).
// ALL loop loads via asm: B depth-1 double-buffer (E/O parity sets),
// x depth-2; vmcnt(10) steady-state, vmcnt(0) last iter.
__global__ __launch_bounds__(512, 4)
void moe_fused(const float* __restrict__ x,
               const unsigned short* __restrict__ Whp,
               const unsigned short* __restrict__ Wlp,
               float* __restrict__ out, int ntok)
{
    __shared__ float cred[KSPLIT][TOKB * CSTR];   // 34.8 KB, epilogue only

    const int t    = threadIdx.x;
    const int w    = t >> 6;            // wave id = k-split id (0..7)
    const int l    = t & 63;
    const int tok0 = blockIdx.x * TOKB;

    const int ar  = l & 15;             // A row (token)
    const int akb = (l >> 4) * 8;       // k-slice within 32-k chunk

    const float* xa = x + (size_t)(tok0 + ar) * D + w * KRNG + akb;
    const unsigned short* whp = Whp + (size_t)w * 16384 + l * 8;
    const unsigned short* wlp = Wlp + (size_t)w * 16384 + l * 8;

    const f32x4 zz = {0.f, 0.f, 0.f, 0.f};
    f32x4 acc[4] = {zz, zz, zz, zz};

    // parity register sets (named: rule #20). B: 64 VGPR, x: 16 VGPR.
    bf16x8 bEh0, bEh1, bEh2, bEh3, bEl0, bEl1, bEl2, bEl3;
    bf16x8 bOh0, bOh1, bOh2, bOh3, bOl0, bOl1, bOl2, bOl3;
    f4 xE0, xE1, xO0, xO1;

#define BISSUE(CH, S) { \
    GL16(b##S##h0, whp + (size_t)(4*(CH)+0)*512); \
    GL16(b##S##l0, wlp + (size_t)(4*(CH)+0)*512); \
    GL16(b##S##h1, whp + (size_t)(4*(CH)+1)*512); \
    GL16(b##S##l1, wlp + (size_t)(4*(CH)+1)*512); \
    GL16(b##S##h2, whp + (size_t)(4*(CH)+2)*512); \
    GL16(b##S##l2, wlp + (size_t)(4*(CH)+2)*512); \
    GL16(b##S##h3, whp + (size_t)(4*(CH)+3)*512); \
    GL16(b##S##l3, wlp + (size_t)(4*(CH)+3)*512); }

#define XISSUE(CH, R0, R1) { \
    GL16(R0, xa + (CH) * KCH);     \
    GL16(R1, xa + (CH) * KCH + 4); }

    // R0/R1 passed explicitly (no token-pasting next to '.': r14 compile fail)
#define CVTA(R0, R1) \
    unsigned hu0_, hu1_, hu2_, hu3_, lu0_, lu1_, lu2_, lu3_; \
    CVTPAIR(R0.x, R0.y, hu0_, lu0_); \
    CVTPAIR(R0.z, R0.w, hu1_, lu1_); \
    CVTPAIR(R1.x, R1.y, hu2_, lu2_); \
    CVTPAIR(R1.z, R1.w, hu3_, lu3_); \
    const u32x4 hv_ = {hu0_, hu1_, hu2_, hu3_}; \
    const u32x4 lv_ = {lu0_, lu1_, lu2_, lu3_}; \
    const bf16x8 ah = __builtin_bit_cast(bf16x8, hv_); \
    const bf16x8 al = __builtin_bit_cast(bf16x8, lv_);

#define MFMAS(S) { \
    acc[0] = __builtin_amdgcn_mfma_f32_16x16x32_bf16(ah, b##S##h0, acc[0], 0, 0, 0); \
    acc[0] = __builtin_amdgcn_mfma_f32_16x16x32_bf16(ah, b##S##l0, acc[0], 0, 0, 0); \
    acc[0] = __builtin_amdgcn_mfma_f32_16x16x32_bf16(al, b##S##h0, acc[0], 0, 0, 0); \
    acc[1] = __builtin_amdgcn_mfma_f32_16x16x32_bf16(ah, b##S##h1, acc[1], 0, 0, 0); \
    acc[1] = __builtin_amdgcn_mfma_f32_16x16x32_bf16(ah, b##S##l1, acc[1], 0, 0, 0); \
    acc[1] = __builtin_amdgcn_mfma_f32_16x16x32_bf16(al, b##S##h1, acc[1], 0, 0, 0); \
    acc[2] = __builtin_amdgcn_mfma_f32_16x16x32_bf16(ah, b##S##h2, acc[2], 0, 0, 0); \
    acc[2] = __builtin_amdgcn_mfma_f32_16x16x32_bf16(ah, b##S##l2, acc[2], 0, 0, 0); \
    acc[2] = __builtin_amdgcn_mfma_f32_16x16x32_bf16(al, b##S##h2, acc[2], 0, 0, 0); \
    acc[3] = __builtin_amdgcn_mfma_f32_16x16x32_bf16(ah, b##S##h3, acc[3], 0, 0, 0); \
    acc[3] = __builtin_amdgcn_mfma_f32_16x16x32_bf16(ah, b##S##l3, acc[3], 0, 0, 0); \
    acc[3] = __builtin_amdgcn_mfma_f32_16x16x32_bf16(al, b##S##h3, acc[3], 0, 0, 0); }

    // steady iter ch: issue B(ch+1) -> opposite set; wait; CVT x(ch);
    // refill X(ch+2) into same x-set (just freed by CVT); MFMA on B(ch).
#define ITER_FULL(CH, S, OS, R0, R1) { \
    BISSUE((CH) + 1, OS) \
    WAIT10 \
    CVTA(R0, R1) \
    XISSUE((CH) + 2, R0, R1) \
    MFMAS(S) }

#define ITER_NOX(CH, S, OS, R0, R1) { \
    BISSUE((CH) + 1, OS) \
    WAIT10 \
    CVTA(R0, R1) \
    MFMAS(S) }

#define ITER_LAST(CH, S, R0, R1) { \
    WAIT0 \
    CVTA(R0, R1) \
    MFMAS(S) }

    // prologue: B0 -> E set; X0 -> xE; X1 -> xO  (FIFO order matters)
    BISSUE(0, E)
    XISSUE(0, xE0, xE1)
    XISSUE(1, xO0, xO1)

    ITER_FULL(0, E, O, xE0, xE1)
    ITER_FULL(1, O, E, xO0, xO1)
    ITER_FULL(2, E, O, xE0, xE1)
    ITER_FULL(3, O, E, xO0, xO1)
    ITER_FULL(4, E, O, xE0, xE1)
    ITER_FULL(5, O, E, xO0, xO1)
    ITER_NOX (6, E, O, xE0, xE1)
    ITER_LAST(7, O, xO0, xO1)

#undef BISSUE
#undef XISSUE
#undef CVTA
#undef MFMAS
#undef ITER_FULL
#undef ITER_NOX
#undef ITER_LAST

    // ---- per-wave partials -> LDS ----
    // C/D layout (verified r4): token = (l>>4)*4 + r, expert = et*16 + (l&15)
#pragma unroll
    for (int et = 0; et < 4; ++et)
#pragma unroll
        for (int r = 0; r < 4; ++r) {
            const int tokl = (l >> 4) * 4 + r;
            cred[w][tokl * CSTR + et * 16 + (l & 15)] = acc[et][r];
        }
    __syncthreads();

    // ---- reduce 8 k-splits + top-2 + softmax (128 active threads) ----
    if (t < TOKB * 8) {
        const int tokl = t >> 3;        // 0..15
        const int eg   = t & 7;         // expert octet
        f4 s0 = {0.f,0.f,0.f,0.f}, s1 = {0.f,0.f,0.f,0.f};
#pragma unroll
        for (int ww = 0; ww < KSPLIT; ++ww) {
            const float* cw = &cred[ww][tokl * CSTR + eg * 8];
            s0 += *(const f4*)cw;
            s1 += *(const f4*)(cw + 4);
        }
        const float vv[8] = {s0.x, s0.y, s0.z, s0.w, s1.x, s1.y, s1.z, s1.w};
        float m1 = -INFINITY, m2 = -INFINITY;
        int i1 = 0, i2 = 0;
#pragma unroll
        for (int j = 0; j < 8; ++j) {   // ids ascending: strict > = lowest-index tie-break
            const float v = vv[j];
            const int id = eg * 8 + j;
            if (v > m1)      { m2 = m1; i2 = i1; m1 = v; i1 = id; }
            else if (v > m2) { m2 = v;  i2 = id; }
        }
#pragma unroll
        for (int m = 1; m < 8; m <<= 1) {
            const float om1 = __shfl_xor(m1, m);
            const int   oi1 = __shfl_xor(i1, m);
            const float om2 = __shfl_xor(m2, m);
            const int   oi2 = __shfl_xor(i2, m);
            const bool b1 = (om1 > m1) || (om1 == m1 && oi1 < i1);
            const float c2v = b1 ? m1 : om1;  const int c2i = b1 ? i1 : oi1;
            const float c3v = b1 ? om2 : m2;  const int c3i = b1 ? oi2 : i2;
            if (b1) { m1 = om1; i1 = oi1; }
            const bool b2 = (c3v > c2v) || (c3v == c2v && c3i < c2i);
            m2 = b2 ? c3v : c2v;  i2 = b2 ? c3i : c2i;
        }
        if (eg == 0) {
            const int tok = tok0 + tokl;
            out[(size_t)tok * 2 + 0] = (float)i1;
            out[(size_t)tok * 2 + 1] = (float)i2;
            const float p1 = 1.0f / (1.0f + expf(m2 - m1));   // stable: m2 <= m1
            float* vals = out + (size_t)ntok * 2;
            vals[(size_t)tok * 2 + 0] = p1;
            vals[(size_t)tok * 2 + 1] = 1.0f - p1;
        }
    }
}

extern "C" void kernel_launch(void* const* d_in, const int* in_sizes, int n_in,
                              void* d_out, int out_size, void* d_ws, size_t ws_size,
                              hipStream_t stream)
{
    const float* x = (const float*)d_in[0];
    const float* W = (const float*)d_in[1];
    float* out = (float*)d_out;
    unsigned short* Whp = (unsigned short*)d_ws;
    unsigned short* Wlp = Whp + (size_t)NE * D;

    const int ntok = in_sizes[0] / D;                 // 16384
    wprep<<<(NE * D) / 256, 256, 0, stream>>>(W, Whp, Wlp);
    moe_fused<<<ntok / TOKB, 512, 0, stream>>>(x, Whp, Wlp, out, ntok);
}

// Round 17
// 43.275 us; speedup vs baseline: 1.0684x; 1.0519x over previous
//
#include <hip/hip_runtime.h>
#include <hip/hip_bf16.h>
#include <math.h>

typedef float f4 __attribute__((ext_vector_type(4)));
typedef float f32x4 __attribute__((ext_vector_type(4)));
typedef short bf16x8 __attribute__((ext_vector_type(8)));
typedef unsigned int u32x4 __attribute__((ext_vector_type(4)));

#define D      2048
#define NE     64
#define TPW    16               // tokens per wave
#define NWAVE  8                // waves per block -> 128 tokens per block
#define TOKB   (TPW * NWAVE)
#define KS     8                // k-split across blocks
#define KRNG   (D / KS)         // 256 k per block
#define KCH    32               // k per chunk
#define NCH    (KRNG / KCH)     // 8 chunks

#define AS1C(p) ((const __attribute__((address_space(1))) void*)(p))
#define AS3(p)  ((__attribute__((address_space(3))) void*)(p))

__device__ __forceinline__ unsigned short bf16rne(float f) {
    unsigned int u = __builtin_bit_cast(unsigned int, f);
    u += 0x7fffu + ((u >> 16) & 1u);
    return (unsigned short)(u >> 16);
}
__device__ __forceinline__ float bf2f(unsigned short h) {
    unsigned int u = (unsigned int)h << 16;
    return __builtin_bit_cast(float, u);
}

// ---- kernel 0: W -> packed bf16 hi/lo in MFMA B-frag order ----
// Wpk[(kc*4 + et)*512 + l*8 + j] = W[et*16 + (l&15)][kc*32 + (l>>4)*8 + j]
__global__ __launch_bounds__(256)
void wprep(const float* __restrict__ W,
           unsigned short* __restrict__ Whp,
           unsigned short* __restrict__ Wlp)
{
    const int i  = blockIdx.x * 256 + threadIdx.x;   // 131072
    const int j  = i & 7;
    const int l  = (i >> 3) & 63;
    const int et = (i >> 9) & 3;
    const int kc = i >> 11;
    const int e  = et * 16 + (l & 15);
    const int k  = kc * 32 + (l >> 4) * 8 + j;
    const float w = W[(size_t)e * D + k];
    const unsigned short h = bf16rne(w);
    Whp[i] = h;
    Wlp[i] = bf16rne(w - bf2f(h));
}

// hi/lo split of a float pair via HW v_cvt_pk_bf16_f32.
#define CVTPAIR(F0, F1, HOUT, LOUT) {                                        \
    __hip_bfloat162 hp_ = __float22bfloat162_rn(make_float2((F0), (F1)));    \
    unsigned hu_; __builtin_memcpy(&hu_, &hp_, 4);                           \
    const float h0_ = __builtin_bit_cast(float, hu_ << 16);                  \
    const float h1_ = __builtin_bit_cast(float, hu_ & 0xffff0000u);          \
    __hip_bfloat162 lp_ = __float22bfloat162_rn(                             \
        make_float2((F0) - h0_, (F1) - h1_));                                \
    unsigned lu_; __builtin_memcpy(&lu_, &lp_, 4);                           \
    HOUT = hu_;                                                              \
    LOUT = lu_;                                                              \
}

// ---- kernel 1: W-in-LDS GEMM partials (NO inline asm — r16 crash lesson) ----
// Block = 8 waves x 16 tokens over ONE k-range (KS=8 split across blocks).
// W-slice (64 KB, frag order) staged ONCE via global_load_lds; B-frags come
// from LDS (ds_read_b128, linear lanes = conflict-free) — W off the vmem/TA
// path. In-loop vmem: 2 plain x-loads per wave-chunk (depth-2 parity regs,
// compiler-managed waits).
__global__ __launch_bounds__(512, 4)
void moe_gemm(const float* __restrict__ x,
              const unsigned short* __restrict__ Whp,
              const unsigned short* __restrict__ Wlp,
              float* __restrict__ part, int ntok)
{
    __shared__ unsigned short Wlds[NCH][4][2][512];   // 64 KB

    const int t    = threadIdx.x;
    const int w    = t >> 6;            // wave id (0..7)
    const int l    = t & 63;
    const int mbc  = ntok / TOKB;       // 128 m-blocks
    const int mb   = blockIdx.x % mbc;
    const int ks   = blockIdx.x / mbc;  // k-split id
    const int tok0 = mb * TOKB;

    const int ar  = l & 15;             // A row (token within wave tile)
    const int akb = (l >> 4) * 8;       // k-slice within 32-k chunk

    // ---- stage W-slice: wave w stages chunk kc=w (4 et x hi/lo = 8 loads) ----
    {
        const size_t kcg = (size_t)(ks * NCH + w) * 4;   // global kc base
#pragma unroll
        for (int et = 0; et < 4; ++et) {
            __builtin_amdgcn_global_load_lds(
                AS1C(Whp + (kcg + et) * 512 + l * 8),
                AS3(&Wlds[w][et][0][0]), 16, 0, 0);
            __builtin_amdgcn_global_load_lds(
                AS1C(Wlp + (kcg + et) * 512 + l * 8),
                AS3(&Wlds[w][et][1][0]), 16, 0, 0);
        }
    }

    const float* xa = x + (size_t)(tok0 + w * TPW + ar) * D + ks * KRNG + akb;

    // depth-2 parity prefetch (plain loads; issued before the barrier)
    f4 xE0 = *(const f4*)(xa);
    f4 xE1 = *(const f4*)(xa + 4);
    f4 xO0 = *(const f4*)(xa + KCH);
    f4 xO1 = *(const f4*)(xa + KCH + 4);

    __syncthreads();                    // W staged (barrier drains vmcnt)

    const f32x4 zz = {0.f, 0.f, 0.f, 0.f};
    f32x4 acc[4] = {zz, zz, zz, zz};

#define CVTA(R0, R1) \
    unsigned hu0_, hu1_, hu2_, hu3_, lu0_, lu1_, lu2_, lu3_; \
    CVTPAIR(R0.x, R0.y, hu0_, lu0_); \
    CVTPAIR(R0.z, R0.w, hu1_, lu1_); \
    CVTPAIR(R1.x, R1.y, hu2_, lu2_); \
    CVTPAIR(R1.z, R1.w, hu3_, lu3_); \
    const u32x4 hv_ = {hu0_, hu1_, hu2_, hu3_}; \
    const u32x4 lv_ = {lu0_, lu1_, lu2_, lu3_}; \
    const bf16x8 ah = __builtin_bit_cast(bf16x8, hv_); \
    const bf16x8 al = __builtin_bit_cast(bf16x8, lv_);

    // one chunk: CVT A, refill x(+2) into freed regs, B from LDS, 12 MFMA
#define CHUNK(CH, R0, R1, REFILL) { \
    CVTA(R0, R1) \
    if (REFILL) { R0 = *(const f4*)(xa + ((CH) + 2) * KCH); \
                  R1 = *(const f4*)(xa + ((CH) + 2) * KCH + 4); } \
    _Pragma("unroll") \
    for (int et = 0; et < 4; ++et) { \
        const bf16x8 bh = *(const bf16x8*)&Wlds[CH][et][0][l * 8]; \
        const bf16x8 bl = *(const bf16x8*)&Wlds[CH][et][1][l * 8]; \
        acc[et] = __builtin_amdgcn_mfma_f32_16x16x32_bf16(ah, bh, acc[et], 0, 0, 0); \
        acc[et] = __builtin_amdgcn_mfma_f32_16x16x32_bf16(ah, bl, acc[et], 0, 0, 0); \
        acc[et] = __builtin_amdgcn_mfma_f32_16x16x32_bf16(al, bh, acc[et], 0, 0, 0); \
    } }

    CHUNK(0, xE0, xE1, 1)
    CHUNK(1, xO0, xO1, 1)
    CHUNK(2, xE0, xE1, 1)
    CHUNK(3, xO0, xO1, 1)
    CHUNK(4, xE0, xE1, 1)
    CHUNK(5, xO0, xO1, 1)
    CHUNK(6, xE0, xE1, 0)
    CHUNK(7, xO0, xO1, 0)

#undef CVTA
#undef CHUNK

    // ---- store partials: part[ks][tok][e] ----
    // C/D layout (verified r4): token = (l>>4)*4 + r, expert = et*16 + (l&15)
    float* pp = part + ((size_t)ks * ntok + tok0 + w * TPW) * NE;
#pragma unroll
    for (int et = 0; et < 4; ++et)
#pragma unroll
        for (int r = 0; r < 4; ++r)
            pp[(size_t)((l >> 4) * 4 + r) * NE + et * 16 + (l & 15)] = acc[et][r];
}

// ---- kernel 2: reduce KS partials + top-2 + softmax ----
// 8 lanes per token (expert octets), r4-proven scan + butterfly.
__global__ __launch_bounds__(256)
void moe_top2(const float* __restrict__ part,
              float* __restrict__ out, int ntok)
{
    const int t   = threadIdx.x;
    const int tok = blockIdx.x * 32 + (t >> 3);
    const int eg  = t & 7;

    f4 s0 = {0.f,0.f,0.f,0.f}, s1 = {0.f,0.f,0.f,0.f};
#pragma unroll
    for (int ks = 0; ks < KS; ++ks) {
        const float* p = part + ((size_t)ks * ntok + tok) * NE + eg * 8;
        s0 += *(const f4*)p;
        s1 += *(const f4*)(p + 4);
    }
    const float vv[8] = {s0.x, s0.y, s0.z, s0.w, s1.x, s1.y, s1.z, s1.w};
    float m1 = -INFINITY, m2 = -INFINITY;
    int i1 = 0, i2 = 0;
#pragma unroll
    for (int j = 0; j < 8; ++j) {       // ids ascending: strict > = lowest-index tie-break
        const float v = vv[j];
        const int id = eg * 8 + j;
        if (v > m1)      { m2 = m1; i2 = i1; m1 = v; i1 = id; }
        else if (v > m2) { m2 = v;  i2 = id; }
    }
#pragma unroll
    for (int m = 1; m < 8; m <<= 1) {
        const float om1 = __shfl_xor(m1, m);
        const int   oi1 = __shfl_xor(i1, m);
        const float om2 = __shfl_xor(m2, m);
        const int   oi2 = __shfl_xor(i2, m);
        const bool b1 = (om1 > m1) || (om1 == m1 && oi1 < i1);
        const float c2v = b1 ? m1 : om1;  const int c2i = b1 ? i1 : oi1;
        const float c3v = b1 ? om2 : m2;  const int c3i = b1 ? oi2 : i2;
        if (b1) { m1 = om1; i1 = oi1; }
        const bool b2 = (c3v > c2v) || (c3v == c2v && c3i < c2i);
        m2 = b2 ? c3v : c2v;  i2 = b2 ? c3i : c2i;
    }
    if (eg == 0) {
        out[(size_t)tok * 2 + 0] = (float)i1;
        out[(size_t)tok * 2 + 1] = (float)i2;
        const float p1 = 1.0f / (1.0f + expf(m2 - m1));   // stable: m2 <= m1
        float* vals = out + (size_t)ntok * 2;
        vals[(size_t)tok * 2 + 0] = p1;
        vals[(size_t)tok * 2 + 1] = 1.0f - p1;
    }
}

extern "C" void kernel_launch(void* const* d_in, const int* in_sizes, int n_in,
                              void* d_out, int out_size, void* d_ws, size_t ws_size,
                              hipStream_t stream)
{
    const float* x = (const float*)d_in[0];
    const float* W = (const float*)d_in[1];
    float* out = (float*)d_out;
    unsigned short* Whp = (unsigned short*)d_ws;
    unsigned short* Wlp = Whp + (size_t)NE * D;
    float* part = (float*)(Wlp + (size_t)NE * D);

    const int ntok = in_sizes[0] / D;                 // 16384
    wprep<<<(NE * D) / 256, 256, 0, stream>>>(W, Whp, Wlp);
    moe_gemm<<<(ntok / TOKB) * KS, 512, 0, stream>>>(x, Whp, Wlp, part, ntok);
    moe_top2<<<ntok / 32, 256, 0, stream>>>(part, out, ntok);
}